// Round 9
// baseline (96.344 us; speedup 1.0000x reference)
//
#include <hip/hip_runtime.h>
#include <hip/hip_bf16.h>

// ---- problem constants (match reference) ----
#define HIN   721
#define WIN   1440
#define HOUT_ 361
#define WOUT_ 720
#define NB    4
#define CIN_  8
#define COUT_ 32
#define KT    9
#define NNZ_  32
// derived: PSCALE = 2, base_row(x) = 2x exactly, cols in [0,16)
// q = c*10 + 2s + e  (80 values), j = col>>1 (8 values)

typedef short  bsh8   __attribute__((ext_vector_type(8)));   // 8 bf16 (4 VGPR) MFMA frag
typedef float  f32x16 __attribute__((ext_vector_type(16)));  // 32x32 MFMA acc
typedef unsigned int u32x4 __attribute__((ext_vector_type(4)));

static __device__ __forceinline__ unsigned short f2bf(float f) {
  unsigned u = __builtin_bit_cast(unsigned, f);
  u += 0x7fffu + ((u >> 16) & 1u);      // RNE
  return (unsigned short)(u >> 16);
}

static __device__ __forceinline__ unsigned pack2(float a, float b) {
  __hip_bfloat162 h = __float22bfloat162_rn(make_float2(a, b));
  unsigned u; __builtin_memcpy(&u, &h, 4);
  return u;                              // a -> low 16, b -> high 16
}

// =====================================================================
// K1: build combined coefficients (unchanged — correct & fast).
//   C[x][o][q][j] = sum over taps (k,n) hitting (s,e,j) of w[o,c,k]*psi[k,x,n]
// =====================================================================
__global__ __launch_bounds__(256) void coeff_kernel(
    const int*   __restrict__ psi_idx,
    const float* __restrict__ psi_vals,
    const float* __restrict__ weight,
    unsigned short* __restrict__ Cg)
{
  __shared__ float Cl[256 * 81];           // 82944 B, stride 81 -> 2-way max
  __shared__ float wl[COUT_ * CIN_ * KT];  // 9216 B
  __shared__ float S[KT][80];              // 2880 B

  const int x = blockIdx.x, tid = threadIdx.x;

  for (int i = tid; i < KT * 80; i += 256) ((float*)S)[i] = 0.f;
  for (int i = tid; i < COUT_ * CIN_ * KT; i += 256) wl[i] = weight[i];
  __syncthreads();

  for (int i = tid; i < KT * NNZ_; i += 256) {   // scatter all 288 taps
    int k = i >> 5, n = i & 31;
    int gi  = (k * HOUT_ + x) * NNZ_ + n;
    int idx = psi_idx[gi];
    int r   = idx / WIN;
    int col = idx - r * WIN;               // in [0,16)
    int s   = r - 2 * x + 2;               // in [0,4] after reference clip
    int slot = (s * 2 + (col & 1)) * 8 + (col >> 1);
    atomicAdd(&S[k][slot], psi_vals[gi]);
  }
  __syncthreads();

  { // dense combine: thread owns (o = tid>>3, c = tid&7)
    const float* wrow = &wl[tid * KT];
    float w[KT];
    #pragma unroll
    for (int k = 0; k < KT; ++k) w[k] = wrow[k];
    float* seg = &Cl[tid * 81];
    #pragma unroll
    for (int slot = 0; slot < 80; ++slot) {
      float acc = 0.f;
      #pragma unroll
      for (int k = 0; k < KT; ++k) acc += w[k] * S[k][slot];
      seg[slot] = acc;
    }
  }
  __syncthreads();

  // writeback as 16B chunks: Cg[((x*8+j)*10+qb)*32+o][qi0..7]
  for (int chunk = tid; chunk < 8 * 10 * 32; chunk += 256) {
    int j   = chunk / 320;
    int rem = chunk - j * 320;
    int qb  = rem >> 5, o = rem & 31;
    u32x4 pack;
    #pragma unroll
    for (int h = 0; h < 4; ++h) {
      int q0 = qb * 8 + 2 * h;
      int c0 = q0 / 10, ql0 = q0 - c0 * 10;
      int q1 = q0 + 1;
      int c1 = q1 / 10, ql1 = q1 - c1 * 10;
      unsigned lo = f2bf(Cl[(o * CIN_ + c0) * 81 + ql0 * 8 + j]);
      unsigned hi = f2bf(Cl[(o * CIN_ + c1) * 81 + ql1 * 8 + j]);
      pack[h] = lo | (hi << 16);
    }
    *(u32x4*)&Cg[((size_t)x * 2560 + (size_t)((j * 10 + qb) * 32 + o)) * 8] = pack;
  }
}

// =====================================================================
// K2: main compute. R8 geometry (PB=256, RST=176 no-swizzle, 3 blocks/CU)
// restructured as a 2-phase T14 pipeline over LDS q-chunks:
//   Phase A: stage chunks 0..5 -> barrier -> MFMA (j, kb 0..2)
//   Phase B: global loads ISSUED before barrier 1 (latency hides under
//            loop-1's ~48 MFMAs), ds_write AFTER loop 1, barrier,
//            MFMA (j, kb 3..4).
// Reduction order over (j,kb) is associative-free, acc chain continues.
// =====================================================================
#define PB   256
#define ROWS 264            // max row read = 262
#define RST  176            // 176 mod 128 = 48 -> b128 reads at bank floor

__global__ __launch_bounds__(256, 3) void disco_main_kernel(
    const float* __restrict__ x,
    const unsigned short* __restrict__ Cg,
    float* __restrict__ out)
{
  __shared__ __align__(16) unsigned char Ut[ROWS * RST];  // 46464 B

  // ---- bijective XCD-chunked decode (nwg = 4332 = 8*541 + 4, m204) ----
  const int g   = blockIdx.x;
  const int xcd = g & 7, lin = g >> 3;
  const int swz = (xcd < 4) ? xcd * 542 + lin : 4 * 542 + (xcd - 4) * 541 + lin;
  const int xo  = swz / 12;
  const int rem = swz - xo * 12;
  const int pt  = rem % 3;          // 0..2
  const int b   = rem / 3;          // 0..3
  const int p0  = pt * PB;
  const int tid = threadIdx.x;

  const int lane = tid & 63;
  const int wv   = tid >> 6;        // 0..3: 64-wide p slice
  const int half = lane >> 5;       // k-slice half (chunk parity)
  const int l31  = lane & 31;
  const int wbase = wv * 64;

  const unsigned short* cgx = Cg + (size_t)xo * 2560 * 8
                                 + (size_t)(half * 32 + l31) * 8;

  // ---- loop-1 A-frags (kb 0..2), j=0,1: issued first, overlap staging ----
  bsh8 a0[3], a1[3];
  #pragma unroll
  for (int kb = 0; kb < 3; ++kb) a0[kb] = *(const bsh8*)&cgx[kb * 512];
  #pragma unroll
  for (int kb = 0; kb < 3; ++kb) a1[kb] = *(const bsh8*)&cgx[2560 + kb * 512];

  const float* xb = x + (size_t)b * (CIN_ * HIN * WIN);

  int rr[5];
  #pragma unroll
  for (int s = 0; s < 5; ++s) {
    int r = 2 * xo + s - 2;
    rr[s] = r < 0 ? 0 : (r > HIN - 1 ? HIN - 1 : r);
  }

  // ================= Phase A: stage chunks 0..5 (units 0..791) ==========
  // unit u: ch = u/132, rp = u%132 -> rows 2rp, 2rp+1; 4 float4 loads
  {
    float4 v[3][4];
    #pragma unroll
    for (int pass = 0; pass < 3; ++pass) {
      const int u  = tid + pass * 256;         // < 768 < 792
      const int ch = u / 132, rp = u - ch * 132;
      int cw = p0 + 2 * rp; if (cw >= WOUT_) cw -= WOUT_;
      #pragma unroll
      for (int m = 0; m < 4; ++m) {
        int qp = 4 * ch + m, c = (qp * 205) >> 10, s = qp - c * 5;
        v[pass][m] = *(const float4*)&xb[(size_t)(c * HIN + rr[s]) * WIN + 2 * cw];
      }
    }
    float4 vt[4];
    const bool tailA = tid < 24;               // units 768..791
    {
      const int u  = tailA ? (768 + tid) : 768;
      const int ch = u / 132, rp = u - ch * 132;
      int cw = p0 + 2 * rp; if (cw >= WOUT_) cw -= WOUT_;
      if (tailA) {
        #pragma unroll
        for (int m = 0; m < 4; ++m) {
          int qp = 4 * ch + m, c = (qp * 205) >> 10, s = qp - c * 5;
          vt[m] = *(const float4*)&xb[(size_t)(c * HIN + rr[s]) * WIN + 2 * cw];
        }
      }
    }
    #pragma unroll
    for (int pass = 0; pass < 3; ++pass) {
      const int u  = tid + pass * 256;
      const int ch = u / 132, rp = u - ch * 132;
      u32x4 lo, hi;
      #pragma unroll
      for (int m = 0; m < 4; ++m) { lo[m] = pack2(v[pass][m].x, v[pass][m].y);
                                    hi[m] = pack2(v[pass][m].z, v[pass][m].w); }
      int byte0 = (2 * rp) * RST + ch * 16;
      *(u32x4*)&Ut[byte0]       = lo;
      *(u32x4*)&Ut[byte0 + RST] = hi;
    }
    if (tailA) {
      const int u  = 768 + tid;
      const int ch = u / 132, rp = u - ch * 132;
      u32x4 lo, hi;
      #pragma unroll
      for (int m = 0; m < 4; ++m) { lo[m] = pack2(vt[m].x, vt[m].y);
                                    hi[m] = pack2(vt[m].z, vt[m].w); }
      int byte0 = (2 * rp) * RST + ch * 16;
      *(u32x4*)&Ut[byte0]       = lo;
      *(u32x4*)&Ut[byte0 + RST] = hi;
    }
  }

  // ===== Phase B loads ISSUED NOW (units 792..1319): land during loop 1 ==
  float4 vB[2][4], vBt[4];
  int uB[2], uBt;
  const bool tailB = tid < 16;                 // units 1304..1319
  #pragma unroll
  for (int pass = 0; pass < 2; ++pass) {
    const int u  = 792 + tid + pass * 256;     // < 1304
    uB[pass] = u;
    const int ch = u / 132, rp = u - ch * 132;
    int cw = p0 + 2 * rp; if (cw >= WOUT_) cw -= WOUT_;
    #pragma unroll
    for (int m = 0; m < 4; ++m) {
      int qp = 4 * ch + m, c = (qp * 205) >> 10, s = qp - c * 5;
      vB[pass][m] = *(const float4*)&xb[(size_t)(c * HIN + rr[s]) * WIN + 2 * cw];
    }
  }
  {
    uBt = tailB ? (1304 + tid) : 1304;
    const int ch = uBt / 132, rp = uBt - ch * 132;
    int cw = p0 + 2 * rp; if (cw >= WOUT_) cw -= WOUT_;
    if (tailB) {
      #pragma unroll
      for (int m = 0; m < 4; ++m) {
        int qp = 4 * ch + m, c = (qp * 205) >> 10, s = qp - c * 5;
        vBt[m] = *(const float4*)&xb[(size_t)(c * HIN + rr[s]) * WIN + 2 * cw];
      }
    }
  }

  // ---- loop-2 A-frags (kb 3..4), j=0,1: issue before barrier too ----
  bsh8 c0[2], c1[2];
  #pragma unroll
  for (int i = 0; i < 2; ++i) c0[i] = *(const bsh8*)&cgx[(3 + i) * 512];
  #pragma unroll
  for (int i = 0; i < 2; ++i) c1[i] = *(const bsh8*)&cgx[2560 + (3 + i) * 512];

  __syncthreads();                             // phase A visible

  // ================= MFMA loop 1: (j, kb 0..2) ==========================
  f32x16 acc0 = {};
  f32x16 acc1 = {};

  #pragma unroll
  for (int j = 0; j < 8; ++j) {
    bsh8 a2[3];
    if (j < 6) {
      #pragma unroll
      for (int kb = 0; kb < 3; ++kb)
        a2[kb] = *(const bsh8*)&cgx[(j + 2) * 2560 + kb * 512];
    }
    const int rb0 = (wbase + l31 + j) * RST;
    const int rb1 = rb0 + 32 * RST;
    #pragma unroll
    for (int kb = 0; kb < 3; ++kb) {
      const int cho = (2 * kb + half) * 16;
      bsh8 b0 = *(const bsh8*)&Ut[rb0 + cho];
      acc0 = __builtin_amdgcn_mfma_f32_32x32x16_bf16(a0[kb], b0, acc0, 0, 0, 0);
      bsh8 b1 = *(const bsh8*)&Ut[rb1 + cho];
      acc1 = __builtin_amdgcn_mfma_f32_32x32x16_bf16(a0[kb], b1, acc1, 0, 0, 0);
    }
    #pragma unroll
    for (int kb = 0; kb < 3; ++kb) { a0[kb] = a1[kb]; a1[kb] = a2[kb]; }
  }

  // ================= Phase B write-late + barrier =======================
  #pragma unroll
  for (int pass = 0; pass < 2; ++pass) {
    const int u  = uB[pass];
    const int ch = u / 132, rp = u - ch * 132;
    u32x4 lo, hi;
    #pragma unroll
    for (int m = 0; m < 4; ++m) { lo[m] = pack2(vB[pass][m].x, vB[pass][m].y);
                                  hi[m] = pack2(vB[pass][m].z, vB[pass][m].w); }
    int byte0 = (2 * rp) * RST + ch * 16;
    *(u32x4*)&Ut[byte0]       = lo;
    *(u32x4*)&Ut[byte0 + RST] = hi;
  }
  if (tailB) {
    const int ch = uBt / 132, rp = uBt - ch * 132;
    u32x4 lo, hi;
    #pragma unroll
    for (int m = 0; m < 4; ++m) { lo[m] = pack2(vBt[m].x, vBt[m].y);
                                  hi[m] = pack2(vBt[m].z, vBt[m].w); }
    int byte0 = (2 * rp) * RST + ch * 16;
    *(u32x4*)&Ut[byte0]       = lo;
    *(u32x4*)&Ut[byte0 + RST] = hi;
  }
  __syncthreads();                             // phase B visible

  // ================= MFMA loop 2: (j, kb 3..4) ==========================
  #pragma unroll
  for (int j = 0; j < 8; ++j) {
    bsh8 c2[2];
    if (j < 6) {
      #pragma unroll
      for (int i = 0; i < 2; ++i)
        c2[i] = *(const bsh8*)&cgx[(j + 2) * 2560 + (3 + i) * 512];
    }
    const int rb0 = (wbase + l31 + j) * RST;
    const int rb1 = rb0 + 32 * RST;
    #pragma unroll
    for (int i = 0; i < 2; ++i) {
      const int cho = (6 + 2 * i + half) * 16;   // kb = 3+i -> ch 6..9
      bsh8 b0 = *(const bsh8*)&Ut[rb0 + cho];
      acc0 = __builtin_amdgcn_mfma_f32_32x32x16_bf16(c0[i], b0, acc0, 0, 0, 0);
      bsh8 b1 = *(const bsh8*)&Ut[rb1 + cho];
      acc1 = __builtin_amdgcn_mfma_f32_32x32x16_bf16(c0[i], b1, acc1, 0, 0, 0);
    }
    #pragma unroll
    for (int i = 0; i < 2; ++i) { c0[i] = c1[i]; c1[i] = c2[i]; }
  }

  // ---- store: D col = l31 -> p, row o = (r&3) + 8*(r>>2) + 4*half ----
  const int p = p0 + wbase + l31;
  #pragma unroll
  for (int r = 0; r < 16; ++r) {
    int o = (r & 3) + 8 * (r >> 2) + 4 * half;
    size_t base = ((size_t)(b * COUT_ + o) * HOUT_ + xo) * WOUT_;
    if (p < WOUT_)
      __builtin_nontemporal_store(acc0[r], &out[base + p]);
    if (p + 32 < WOUT_)
      __builtin_nontemporal_store(acc1[r], &out[base + p + 32]);
  }
}

extern "C" void kernel_launch(void* const* d_in, const int* in_sizes, int n_in,
                              void* d_out, int out_size, void* d_ws, size_t ws_size,
                              hipStream_t stream) {
  const float* x        = (const float*)d_in[0];
  const int*   psi_idx  = (const int*)d_in[1];
  const float* psi_vals = (const float*)d_in[2];
  const float* weight   = (const float*)d_in[3];
  float* out = (float*)d_out;
  unsigned short* Cg = (unsigned short*)d_ws;   // 361*2560*8 bf16 = 14.8 MB

  coeff_kernel<<<dim3(HOUT_), 256, 0, stream>>>(psi_idx, psi_vals, weight, Cg);
  disco_main_kernel<<<dim3(3 * NB * HOUT_), 256, 0, stream>>>(x, Cg, out);
}